// Round 8
// baseline (3138.696 us; speedup 1.0000x reference)
//
#include <hip/hip_runtime.h>

typedef _Float16 h2f __attribute__((ext_vector_type(2)));
typedef _Float16 f16x8 __attribute__((ext_vector_type(8)));
typedef float f32x4 __attribute__((ext_vector_type(4)));
typedef unsigned int u32;
typedef unsigned short u16;

#define B_ 128
#define S_ 1024
#define I_ 256
#define H_ 512
#define O_ 256
#define IH_ 768

#if __has_builtin(__builtin_amdgcn_fdot2)
__device__ __forceinline__ float fdot2u(u32 a, u32 b, float c) {
    return __builtin_amdgcn_fdot2(__builtin_bit_cast(h2f, a),
                                  __builtin_bit_cast(h2f, b), c, false);
}
#else
__device__ __forceinline__ float fdot2u(u32 a, u32 b, float c) {
    h2f av = __builtin_bit_cast(h2f, a), bv = __builtin_bit_cast(h2f, b);
    return c + (float)av.x * (float)bv.x + (float)av.y * (float)bv.y;
}
#endif

__device__ __forceinline__ u32 pack2(float x, float y) {
    return __builtin_bit_cast(u32, __builtin_amdgcn_cvt_pkrtz(x, y));
}
__device__ __forceinline__ u16 f2h(float x) { return __builtin_bit_cast(u16, (_Float16)x); }
__device__ __forceinline__ float h2f_(u16 x) { return (float)__builtin_bit_cast(_Float16, x); }

__device__ __forceinline__ float tanh_fast(float x) {
    float e = __expf(-2.f * fabsf(x));     // e in (0,1] -- no overflow path
    float r = (1.f - e) / (1.f + e);
    return copysignf(r, x);
}

// MFMA helper (phase 1): D = A(16x32)*B(32x16)+C, f16 in / f32 acc.
__device__ __forceinline__ f32x4 mfx(uint4 a, uint4 b, f32x4 c) {
    return __builtin_amdgcn_mfma_f32_16x16x32_f16(
        __builtin_bit_cast(f16x8, a), __builtin_bit_cast(f16x8, b), c, 0, 0, 0);
}
__device__ __forceinline__ f32x4 mf(uint4 a, const uint4* bp, f32x4 c) {
    uint4 b = *bp;
    return mfx(a, b, c);
}

#define REP8(X)  X(0) X(1) X(2) X(3) X(4) X(5) X(6) X(7)
#define REP16(X) REP8(X) X(8) X(9) X(10) X(11) X(12) X(13) X(14) X(15)
// phase-2 banks: arch-VGPR q=0..11, AGPR q=12..41, LDS q=42..48, stream q=49..63
#define REPV12(X) X(0) X(1) X(2) X(3) X(4) X(5) X(6) X(7) X(8) X(9) X(10) X(11)
#define REPA_1(X) X(0) X(1) X(2) X(3) X(4) X(5) X(6) X(7) X(8) X(9) X(10) \
                  X(11) X(12) X(13) X(14)
#define REPA_2(X) X(15) X(16) X(17) X(18) X(19) X(20) X(21) X(22) X(23) X(24) \
                  X(25) X(26) X(27) X(28) X(29)
#define REP30(X) REPA_1(X) REPA_2(X)
#define REPL7(X) X(0) X(1) X(2) X(3) X(4) X(5) X(6)
#define REPS_1(X) X(0) X(1) X(2) X(3) X(4) X(5) X(6) X(7)
#define REPS_2(X) X(8) X(9) X(10) X(11) X(12) X(13) X(14)

// ---------------------------------------------------------------------------
// Workspace layout (bytes):
//   wxb4 @ 0      : 16384 uint4 (256 KB)  Wx octets [q 0..31][col 0..511]
//   whb4 @ 256 KB : 32768 uint4 (512 KB)  Wh octets [q 0..63][n 0..511]
//                   octet q of col n = W[n][256+q*8 .. +7] as f16
//   pre  @ 1 MB   : 128*1024*512 f16 (128 MB)
// ---------------------------------------------------------------------------
#define WXB_OFF 0
#define WHB_OFF (256u << 10)
#define PRE_OFF (1u << 20)

__global__ __launch_bounds__(256) void k_convert(const float* __restrict__ W,
                                                 uint4* __restrict__ wxb4,
                                                 uint4* __restrict__ whb4) {
    int idx = blockIdx.x * 256 + threadIdx.x;       // 0..49151
    if (idx < 16384) {                               // wxb: q = idx>>9 (0..31)
        int q = idx >> 9, col = idx & 511;
        const float4* r = (const float4*)(W + (long)col * IH_ + q * 8);
        float4 u = r[0], v = r[1];
        wxb4[idx] = (uint4){pack2(u.x, u.y), pack2(u.z, u.w),
                            pack2(v.x, v.y), pack2(v.z, v.w)};
    } else {                                         // whb: q = 0..63
        int i2 = idx - 16384;
        int q = i2 >> 9, n = i2 & 511;
        const float4* r = (const float4*)(W + (long)n * IH_ + I_ + q * 8);
        float4 u = r[0], v = r[1];
        whb4[i2] = (uint4){pack2(u.x, u.y), pack2(u.z, u.w),
                           pack2(v.x, v.y), pack2(v.z, v.w)};
    }
}

// ---------------------------------------------------------------------------
// Phase 1 (MFMA GEMM, proven ~40 us in R4-R6 -- unchanged).
// ---------------------------------------------------------------------------
__global__ __launch_bounds__(256) __attribute__((amdgpu_waves_per_eu(2, 2)))
void k_phase1(const float* __restrict__ seq, const uint4* __restrict__ wxb4,
              const float* __restrict__ bias, u16* __restrict__ pre) {
    int w = threadIdx.x >> 6, l = threadIdx.x & 63;
    int lm = l & 15, lq = l >> 4;
    int mb_w = blockIdx.x * 64 + w * 16;
    long xrow = (long)(mb_w + lm) * I_;
#define DECLA1(k) uint4 a##k; { \
        const float4* xp = (const float4*)(seq + xrow + (k)*32 + lq*8); \
        float4 u = xp[0], v = xp[1]; \
        a##k = (uint4){pack2(u.x,u.y), pack2(u.z,u.w), pack2(v.x,v.y), pack2(v.z,v.w)}; }
    REP8(DECLA1)
#undef DECLA1
    int mrow0 = mb_w + lq * 4;
#pragma unroll
    for (int half = 0; half < 2; ++half) {
        int colbase = half * 256;
        const uint4* bptr = wxb4 + colbase + lm;
#define DECLC(n) float bv##n = bias[colbase + (n)*16 + lm]; \
                 f32x4 c##n = {bv##n, bv##n, bv##n, bv##n};
        REP16(DECLC)
#undef DECLC
#define ROW(k,n) c##n = mf(a##k, bptr + ((k)*4 + lq)*512 + (n)*16, c##n);
#define KS(k) ROW(k,0) ROW(k,1) ROW(k,2) ROW(k,3) ROW(k,4) ROW(k,5) ROW(k,6) ROW(k,7) \
              ROW(k,8) ROW(k,9) ROW(k,10) ROW(k,11) ROW(k,12) ROW(k,13) ROW(k,14) ROW(k,15)
        KS(0) KS(1) KS(2) KS(3) KS(4) KS(5) KS(6) KS(7)
#undef KS
#undef ROW
#define STN(n) { long cb = (long)colbase + (n)*16 + lm; \
        pre[(long)(mrow0+0)*H_ + cb] = f2h(c##n[0]); \
        pre[(long)(mrow0+1)*H_ + cb] = f2h(c##n[1]); \
        pre[(long)(mrow0+2)*H_ + cb] = f2h(c##n[2]); \
        pre[(long)(mrow0+3)*H_ + cb] = f2h(c##n[3]); }
        REP16(STN)
#undef STN
    }
}

// ---------------------------------------------------------------------------
// Phase 2: persistent dot2 recurrence, one WG per batch row, 128 WGs x 256
// threads = 4 waves = 1 wave/EU (__launch_bounds__(256,1) -> 512-reg unified
// budget: 256 arch + 256 acc). Thread j owns columns j and j+256 (one
// readlane broadcast feeds both columns' dots). 64 Wh octet-slabs per col:
//   q  0..11 : 12 slabs in NAMED arch u32 (96 regs, asm-opaqued; budget-512
//              finally has arch headroom -- first config where this can fit)
//   q 12..41 : 30 slabs in AGPRs (240 of 256): v_accvgpr_write once;
//              per step v_accvgpr_read -> VGPR -> builtin dot2. gfx950 VOP3P
//              can NOT source AGPRs directly (R7 compile error), so the read
//              is mandatory -- but it's full-rate VALU, far cheaper than the
//              L2 re-stream it replaces (R5: 82 B/cyc/CU).
//   q 42..48 : 7 slabs LDS (56 KB; 64 KB/WG is the architectural cap -- R3)
//   q 49..63 : 15 slabs streamed from L2 (120 KB/step/CU, hidden under VALU)
// h ping-pong in LDS f16[512]; lane l ds_read_b128's h pairs 4l..4l+3; pair
// dword of slab q broadcast from lane q via readlane -> SGPR dot2 src0.
// ---------------------------------------------------------------------------
__global__ __launch_bounds__(256, 1)
void k_phase2(const u16* __restrict__ pre, const uint4* __restrict__ whb4,
              const float* __restrict__ Who, const float* __restrict__ bo,
              float* __restrict__ out) {
    __shared__ __align__(16) uint4 wlds[7 * 512];   // 56 KB, slabs q=42..48
    __shared__ __align__(16) u16 hbuf[2][H_];
    int b = blockIdx.x, j = threadIdx.x, lane = j & 63;

    // --- arch-VGPR bank: 12 slabs x 2 cols = 96 named u32, asm-opaqued ---
#define VDECL(i) \
    uint4 vA##i = whb4[(i) * 512 + j]; uint4 vB##i = whb4[(i) * 512 + j + 256]; \
    u32 vAx##i = vA##i.x, vAy##i = vA##i.y, vAz##i = vA##i.z, vAw##i = vA##i.w; \
    u32 vBx##i = vB##i.x, vBy##i = vB##i.y, vBz##i = vB##i.z, vBw##i = vB##i.w; \
    asm volatile("" : "+v"(vAx##i), "+v"(vAy##i), "+v"(vAz##i), "+v"(vAw##i), \
                      "+v"(vBx##i), "+v"(vBy##i), "+v"(vBz##i), "+v"(vBw##i));
    REPV12(VDECL)
#undef VDECL

    // --- AGPR bank: 30 slabs x 2 cols = 240 AGPRs via v_accvgpr_write ---
#define ADECL(i) u32 gAx##i, gAy##i, gAz##i, gAw##i, gBx##i, gBy##i, gBz##i, gBw##i;
    REP30(ADECL)
#undef ADECL
#define AINIT(i) { uint4 tA = whb4[((i) + 12) * 512 + j]; \
                   uint4 tB = whb4[((i) + 12) * 512 + j + 256]; \
    asm volatile("v_accvgpr_write_b32 %0, %1" : "=a"(gAx##i) : "v"(tA.x)); \
    asm volatile("v_accvgpr_write_b32 %0, %1" : "=a"(gAy##i) : "v"(tA.y)); \
    asm volatile("v_accvgpr_write_b32 %0, %1" : "=a"(gAz##i) : "v"(tA.z)); \
    asm volatile("v_accvgpr_write_b32 %0, %1" : "=a"(gAw##i) : "v"(tA.w)); \
    asm volatile("v_accvgpr_write_b32 %0, %1" : "=a"(gBx##i) : "v"(tB.x)); \
    asm volatile("v_accvgpr_write_b32 %0, %1" : "=a"(gBy##i) : "v"(tB.y)); \
    asm volatile("v_accvgpr_write_b32 %0, %1" : "=a"(gBz##i) : "v"(tB.z)); \
    asm volatile("v_accvgpr_write_b32 %0, %1" : "=a"(gBw##i) : "v"(tB.w)); }
    REP30(AINIT)
#undef AINIT

    // --- LDS bank: 7 slabs ---
#pragma unroll
    for (int s_ = 0; s_ < 7; ++s_) {
        wlds[s_ * 512 + j]       = whb4[(42 + s_) * 512 + j];
        wlds[s_ * 512 + j + 256] = whb4[(42 + s_) * 512 + j + 256];
    }

    const u16* prowA = pre + (long)b * S_ * H_ + j;
    const u16* prowB = prowA + 256;
    hbuf[0][j] = 0; hbuf[0][j + 256] = 0;           // h_{-1} = 0
    __syncthreads();
    u16 pva = prowA[0], pvb = prowB[0];             // pre for t=0
    for (int t = 0; t < S_; ++t) {
        int cur = t & 1, nxt = cur ^ 1;
        long tn = (t + 1 < S_) ? (long)(t + 1) : (long)t;
        int zoff = 0, lz = 0;
        asm volatile("" : "+v"(zoff), "+v"(lz));    // block LICM of banked loads
#define SLOAD(i) uint4 sA##i = whb4[(49 + (i)) * 512 + j + zoff]; \
                 uint4 sB##i = whb4[(49 + (i)) * 512 + j + 256 + zoff];
        REPS_1(SLOAD)                               // stream chunk 1 in flight
        uint4 hv = ((const uint4*)hbuf[cur])[lane]; // lane l: h pairs 4l..4l+3
        u16 npa = prowA[tn * H_], npb = prowB[tn * H_];
        float c0 = h2f_(pva), c1 = 0.f, c2 = 0.f, c3 = 0.f;
        float d0 = h2f_(pvb), d1 = 0.f, d2 = 0.f, d3 = 0.f;
        // arch-resident dots (q = 0..11)
#define VDOT(i) { \
        u32 sx = (u32)__builtin_amdgcn_readlane((int)hv.x, (i)); \
        u32 sy = (u32)__builtin_amdgcn_readlane((int)hv.y, (i)); \
        u32 sz = (u32)__builtin_amdgcn_readlane((int)hv.z, (i)); \
        u32 sw = (u32)__builtin_amdgcn_readlane((int)hv.w, (i)); \
        c0 = fdot2u(sx, vAx##i, c0); c1 = fdot2u(sy, vAy##i, c1); \
        c2 = fdot2u(sz, vAz##i, c2); c3 = fdot2u(sw, vAw##i, c3); \
        d0 = fdot2u(sx, vBx##i, d0); d1 = fdot2u(sy, vBy##i, d1); \
        d2 = fdot2u(sz, vBz##i, d2); d3 = fdot2u(sw, vBw##i, d3); }
        REPV12(VDOT)
#undef VDOT
        // AGPR dots (q = 12+i): read AGPR -> VGPR, then dot
#define ADOT(i) { \
        u32 sx = (u32)__builtin_amdgcn_readlane((int)hv.x, 12 + (i)); \
        u32 sy = (u32)__builtin_amdgcn_readlane((int)hv.y, 12 + (i)); \
        u32 sz = (u32)__builtin_amdgcn_readlane((int)hv.z, 12 + (i)); \
        u32 sw = (u32)__builtin_amdgcn_readlane((int)hv.w, 12 + (i)); \
        u32 rx, ry, rz, rw, qx, qy, qz, qw; \
        asm volatile("v_accvgpr_read_b32 %0, %1" : "=v"(rx) : "a"(gAx##i)); \
        asm volatile("v_accvgpr_read_b32 %0, %1" : "=v"(ry) : "a"(gAy##i)); \
        asm volatile("v_accvgpr_read_b32 %0, %1" : "=v"(rz) : "a"(gAz##i)); \
        asm volatile("v_accvgpr_read_b32 %0, %1" : "=v"(rw) : "a"(gAw##i)); \
        asm volatile("v_accvgpr_read_b32 %0, %1" : "=v"(qx) : "a"(gBx##i)); \
        asm volatile("v_accvgpr_read_b32 %0, %1" : "=v"(qy) : "a"(gBy##i)); \
        asm volatile("v_accvgpr_read_b32 %0, %1" : "=v"(qz) : "a"(gBz##i)); \
        asm volatile("v_accvgpr_read_b32 %0, %1" : "=v"(qw) : "a"(gBw##i)); \
        c0 = fdot2u(sx, rx, c0); c1 = fdot2u(sy, ry, c1); \
        c2 = fdot2u(sz, rz, c2); c3 = fdot2u(sw, rw, c3); \
        d0 = fdot2u(sx, qx, d0); d1 = fdot2u(sy, qy, d1); \
        d2 = fdot2u(sz, qz, d2); d3 = fdot2u(sw, qw, d3); }
        REPA_1(ADOT)                                // AGPR slabs 0..14
        // consume stream chunk 1 (q = 49..56)
#define SDOT(i) { \
        u32 sx = (u32)__builtin_amdgcn_readlane((int)hv.x, 49 + (i)); \
        u32 sy = (u32)__builtin_amdgcn_readlane((int)hv.y, 49 + (i)); \
        u32 sz = (u32)__builtin_amdgcn_readlane((int)hv.z, 49 + (i)); \
        u32 sw = (u32)__builtin_amdgcn_readlane((int)hv.w, 49 + (i)); \
        c0 = fdot2u(sx, sA##i.x, c0); c1 = fdot2u(sy, sA##i.y, c1); \
        c2 = fdot2u(sz, sA##i.z, c2); c3 = fdot2u(sw, sA##i.w, c3); \
        d0 = fdot2u(sx, sB##i.x, d0); d1 = fdot2u(sy, sB##i.y, d1); \
        d2 = fdot2u(sz, sB##i.z, d2); d3 = fdot2u(sw, sB##i.w, d3); }
        REPS_1(SDOT)
        REPS_2(SLOAD)                               // stream chunk 2 in flight
#undef SLOAD
#define LLOAD(i) uint4 tA##i = wlds[(i) * 512 + j + lz]; \
                 uint4 tB##i = wlds[(i) * 512 + j + 256 + lz];
        REPL7(LLOAD)                                // LDS slabs in flight
#undef LLOAD
        REPA_2(ADOT)                                // AGPR slabs 15..29
#undef ADOT
#define LDOT(i) { \
        u32 sx = (u32)__builtin_amdgcn_readlane((int)hv.x, 42 + (i)); \
        u32 sy = (u32)__builtin_amdgcn_readlane((int)hv.y, 42 + (i)); \
        u32 sz = (u32)__builtin_amdgcn_readlane((int)hv.z, 42 + (i)); \
        u32 sw = (u32)__builtin_amdgcn_readlane((int)hv.w, 42 + (i)); \
        c0 = fdot2u(sx, tA##i.x, c0); c1 = fdot2u(sy, tA##i.y, c1); \
        c2 = fdot2u(sz, tA##i.z, c2); c3 = fdot2u(sw, tA##i.w, c3); \
        d0 = fdot2u(sx, tB##i.x, d0); d1 = fdot2u(sy, tB##i.y, d1); \
        d2 = fdot2u(sz, tB##i.z, d2); d3 = fdot2u(sw, tB##i.w, d3); }
        REPL7(LDOT)                                 // LDS slabs q=42..48
#undef LDOT
        REPS_2(SDOT)                                // stream chunk 2 q=57..63
#undef SDOT
        float accA = (c0 + c1) + (c2 + c3);
        float accB = (d0 + d1) + (d2 + d3);
        hbuf[nxt][j]       = f2h(tanh_fast(accA));
        hbuf[nxt][j + 256] = f2h(tanh_fast(accB));
        pva = npa; pvb = npb;
        __syncthreads();
    }
    // final h lives in hbuf[0] (last write: t=1023 -> nxt=0)
    out[(long)B_ * O_ + (long)b * H_ + j]       = h2f_(hbuf[0][j]);
    out[(long)B_ * O_ + (long)b * H_ + j + 256] = h2f_(hbuf[0][j + 256]);
    {                                               // o = h @ W_h2o^T + b_h2o
        float acc = bo[j];
        const float4* wr = (const float4*)(Who + (long)j * H_);
        const u16* hb = hbuf[0];
#pragma unroll 4
        for (int k = 0; k < 128; ++k) {
            float4 wv = wr[k];
            acc += h2f_(hb[4 * k + 0]) * wv.x
                 + h2f_(hb[4 * k + 1]) * wv.y
                 + h2f_(hb[4 * k + 2]) * wv.z
                 + h2f_(hb[4 * k + 3]) * wv.w;
        }
        out[(long)b * O_ + j] = acc;
    }
}

// ---------------------------------------------------------------------------
// Fallback (workspace too small): straightforward fp32, correct but slow.
// ---------------------------------------------------------------------------
__global__ __launch_bounds__(512) void k_fallback(const float* __restrict__ seq,
                                                  const float* __restrict__ W,
                                                  const float* __restrict__ bias,
                                                  const float* __restrict__ Who,
                                                  const float* __restrict__ bo,
                                                  float* __restrict__ out) {
    __shared__ float hb[2][H_];
    int b = blockIdx.x, j = threadIdx.x;
    const float* wrow = W + (long)j * IH_;
    float bj = bias[j];
    hb[0][j] = 0.f;
    __syncthreads();
    for (int t = 0; t < S_; ++t) {
        const float* x = seq + ((long)b * S_ + t) * I_;
        float acc = bj;
        for (int i = 0; i < I_; ++i) acc += x[i] * wrow[i];
        const float* hc = hb[t & 1];
        for (int k = 0; k < H_; ++k) acc += hc[k] * wrow[I_ + k];
        hb[(t & 1) ^ 1][j] = tanh_fast(acc);
        __syncthreads();
    }
    float hj = hb[0][j];
    out[(long)B_ * O_ + (long)b * H_ + j] = hj;
    if (j < O_) {
        float acc = bo[j];
        const float* wr = Who + (long)j * H_;
        for (int k = 0; k < H_; ++k) acc += hb[0][k] * wr[k];
        out[(long)b * O_ + j] = acc;
    }
}

extern "C" void kernel_launch(void* const* d_in, const int* in_sizes, int n_in,
                              void* d_out, int out_size, void* d_ws, size_t ws_size,
                              hipStream_t stream) {
    const float* seq = (const float*)d_in[0];   // (128,1024,256) fp32
    const float* W   = (const float*)d_in[1];   // (512,768) fp32
    const float* bi  = (const float*)d_in[2];   // (512,)
    const float* Who = (const float*)d_in[3];   // (256,512)
    const float* bo  = (const float*)d_in[4];   // (256,)
    float* out = (float*)d_out;                 // 32768 output + 65536 hidden

    const size_t WS_NEED = (size_t)PRE_OFF + (size_t)B_ * S_ * H_ * 2;

    if (ws_size >= WS_NEED) {
        char* ws = (char*)d_ws;
        uint4* wxb4 = (uint4*)(ws + WXB_OFF);
        uint4* whb4 = (uint4*)(ws + WHB_OFF);
        u16*   pre  = (u16*)(ws + PRE_OFF);
        k_convert<<<192, 256, 0, stream>>>(W, wxb4, whb4);
        k_phase1<<<2048, 256, 0, stream>>>(seq, wxb4, bi, pre);
        k_phase2<<<B_, 256, 0, stream>>>(pre, whb4, Who, bo, out);
    } else {
        k_fallback<<<B_, 512, 0, stream>>>(seq, W, bi, Who, bo, out);
    }
}